// Round 2
// baseline (249.540 us; speedup 1.0000x reference)
//
#include <hip/hip_runtime.h>

typedef unsigned short u16;
typedef __attribute__((ext_vector_type(8))) short bf16x8;   // 8 bf16 in 4 VGPRs
typedef __attribute__((ext_vector_type(4))) float f32x4;
typedef __attribute__((ext_vector_type(4))) unsigned int u32x4;

#define DIM 2048

__device__ inline u16 f2bf(float f) {
    unsigned u = __builtin_bit_cast(unsigned, f);
    u = (u + 0x7FFFu + ((u >> 16) & 1u)) >> 16;   // RNE, finite inputs only
    return (u16)u;
}

__device__ inline void gl_lds16(const void* g, void* l) {
    __builtin_amdgcn_global_load_lds(
        (const __attribute__((address_space(1))) unsigned int*)g,
        (__attribute__((address_space(3))) unsigned int*)l, 16, 0, 0);
}

struct c32 { float x, y; };
__device__ inline c32 cmul(c32 a, c32 b) { return {a.x*b.x - a.y*b.y, a.x*b.y + a.y*b.x}; }
__device__ inline float2 cmulf2(float2 a, float2 b) {
    return make_float2(a.x*b.x - a.y*b.y, a.x*b.y + a.y*b.x);
}

__device__ inline int slot2(int i) { return i + (i >> 4); }   // float2 bank-pad

__device__ inline float2 shflx2(float2 v, int m) {
    return make_float2(__shfl_xor(v.x, m, 64), __shfl_xor(v.y, m, 64));
}

// complex butterfly: (u,w) <- (g0*u + g1*w, g2*u + g3*w)
__device__ inline void bfly(float2 g0, float2 g1, float2 g2, float2 g3,
                            float2& u, float2& w) {
    float2 nu, nw;
    nu.x = g0.x*u.x - g0.y*u.y + g1.x*w.x - g1.y*w.y;
    nu.y = g0.x*u.y + g0.y*u.x + g1.x*w.y + g1.y*w.x;
    nw.x = g2.x*u.x - g2.y*u.y + g3.x*w.x - g3.y*w.y;
    nw.y = g2.x*u.y + g2.y*u.x + g3.x*w.y + g3.y*w.x;
    u = nu; w = nw;
}

// ---------------------------------------------------------------------------
// Kernel 1: build T = U^T, one column per block, statevector in LDS (float2).
// Round-15 structure (2 LDS passes per layer):
//  - Layer 0: direct Kronecker product into registers (home layout: thread t
//    owns elements t*8..t*8+7, i.e. bits 2..0 in registers, bits 10..3 = t).
//  - Per layer 1..4:
//      Pass A: round3 on bits {10,9,8} (qubits 0,1,2); ring perm (validated
//              closed form jj=(i^(i>>1))^((i&1)?0x600:0)) inlined in the read
//              addressing -- ptab table deleted.
//      Pass B: contiguous home read (4x ds_read_b128, conflict-free), gates on
//              bits 7..3 (qubits 3..7) via __shfl_xor (wave-local lane bits
//              0..4), gates on bits 2..0 (qubits 8,9,10) in registers.
//    Layer 4's Pass B stores bf16 directly to global (no extra LDS pass).
//  - Barriers: 24 -> 9.  LDS: 19.2 KB -> 8 blocks/CU.
// ---------------------------------------------------------------------------
__global__ __launch_bounds__(256) void build_ut(const float* __restrict__ w,
                                                u16* __restrict__ ut_re,
                                                u16* __restrict__ ut_im) {
    __shared__ alignas(16) float2 gg[55][4];          // 2x2 gates, row-major
    __shared__ alignas(16) float2 V[DIM + (DIM >> 4)];
    const int tid  = threadIdx.x;
    const int lane = tid & 63;
    const int col  = blockIdx.x;

    if (tid < 55) {
        const int layer = tid / 11, q = tid - layer * 11;
        const float WM = 0.63245553203367586f;   // sqrt(2)*5^-0.5
        float hx = 0.5f * WM * w[33*layer + q];
        float hy = 0.5f * WM * w[33*layer + 11 + q];
        float hz = 0.5f * WM * w[33*layer + 22 + q];
        float cx = cosf(hx), sx = sinf(hx);
        float cy = cosf(hy), sy = sinf(hy);
        float cz = cosf(hz), sz = sinf(hz);
        c32 m00{cy*cx,  sy*sx}, m01{-sy*cx, -cy*sx};
        c32 m10{sy*cx, -cy*sx}, m11{ cy*cx, -sy*sx};
        c32 em{cz, -sz}, ep{cz, sz};
        c32 r0 = cmul(em, m00), r1 = cmul(em, m01);
        c32 r2 = cmul(ep, m10), r3 = cmul(ep, m11);
        gg[tid][0] = make_float2(r0.x, r0.y);
        gg[tid][1] = make_float2(r1.x, r1.y);
        gg[tid][2] = make_float2(r2.x, r2.y);
        gg[tid][3] = make_float2(r3.x, r3.y);
    }
    __syncthreads();

    // --- Layer 0: direct Kronecker product of a basis vector (registers) --
    {
        float2 p = gg[0][((((tid >> 7) & 1) << 1)) | ((col >> 10) & 1)];
        #pragma unroll
        for (int b = 9; b >= 3; --b) {
            float2 ge = gg[10 - b][(((tid >> (b - 3)) & 1) << 1) | ((col >> b) & 1)];
            p = cmulf2(p, ge);
        }
        const int c2 = (col >> 2) & 1, c1 = (col >> 1) & 1, c0 = col & 1;
        float2 a0  = cmulf2(p, gg[8][c2]);       // bit2 = 0
        float2 a1  = cmulf2(p, gg[8][2 | c2]);   // bit2 = 1
        float2 b00 = cmulf2(a0, gg[9][c1]);
        float2 b01 = cmulf2(a0, gg[9][2 | c1]);
        float2 b10 = cmulf2(a1, gg[9][c1]);
        float2 b11 = cmulf2(a1, gg[9][2 | c1]);
        float2 g0 = gg[10][c0], g1 = gg[10][2 | c0];
        const int sb = slot2(tid << 3);           // 8 consecutive slots
        V[sb + 0] = cmulf2(b00, g0);
        V[sb + 1] = cmulf2(b00, g1);
        V[sb + 2] = cmulf2(b01, g0);
        V[sb + 3] = cmulf2(b01, g1);
        V[sb + 4] = cmulf2(b10, g0);
        V[sb + 5] = cmulf2(b10, g1);
        V[sb + 6] = cmulf2(b11, g0);
        V[sb + 7] = cmulf2(b11, g1);
    }
    __syncthreads();

    for (int layer = 1; layer < 5; ++layer) {
        const int gb = layer * 11;

        // ---- Pass A: bits {10,9,8} = qubits 0,1,2; ring perm on read ----
        {
            float2 a[8]; int sl[8];
            #pragma unroll
            for (int j = 0; j < 8; ++j) {
                int e  = tid | (j << 8);                 // j0->bit8 j1->bit9 j2->bit10
                sl[j]  = slot2(e);
                int pe = (e ^ (e >> 1)) ^ ((e & 1) ? 0x600 : 0);
                a[j]   = V[slot2(pe)];
            }
            __syncthreads();   // all perm reads done before overwriting V
            {   float2 g0 = gg[gb+0][0], g1 = gg[gb+0][1], g2 = gg[gb+0][2], g3 = gg[gb+0][3];
                bfly(g0,g1,g2,g3, a[0], a[4]); bfly(g0,g1,g2,g3, a[1], a[5]);
                bfly(g0,g1,g2,g3, a[2], a[6]); bfly(g0,g1,g2,g3, a[3], a[7]); }
            {   float2 g0 = gg[gb+1][0], g1 = gg[gb+1][1], g2 = gg[gb+1][2], g3 = gg[gb+1][3];
                bfly(g0,g1,g2,g3, a[0], a[2]); bfly(g0,g1,g2,g3, a[1], a[3]);
                bfly(g0,g1,g2,g3, a[4], a[6]); bfly(g0,g1,g2,g3, a[5], a[7]); }
            {   float2 g0 = gg[gb+2][0], g1 = gg[gb+2][1], g2 = gg[gb+2][2], g3 = gg[gb+2][3];
                bfly(g0,g1,g2,g3, a[0], a[1]); bfly(g0,g1,g2,g3, a[2], a[3]);
                bfly(g0,g1,g2,g3, a[4], a[5]); bfly(g0,g1,g2,g3, a[6], a[7]); }
            #pragma unroll
            for (int j = 0; j < 8; ++j) V[sl[j]] = a[j];
            __syncthreads();
        }

        // ---- Pass B: home layout; bits 7..3 by shuffle, bits 2..0 in reg --
        {
            const int sb = slot2(tid << 3);
            float2 v[8];
            #pragma unroll
            for (int j = 0; j < 8; ++j) v[j] = V[sb + j];

            #pragma unroll
            for (int b = 7; b >= 3; --b) {               // qubit 10-b, gate gb+(10-b)
                const int gq = gb + (10 - b);
                const int m  = 1 << (b - 3);             // lane-xor mask
                const bool hi = (lane & m) != 0;
                float2 g0 = gg[gq][0], g1 = gg[gq][1], g2 = gg[gq][2], g3 = gg[gq][3];
                float2 ca = hi ? g3 : g0;                // x own
                float2 cb = hi ? g2 : g1;                // x partner
                #pragma unroll
                for (int j = 0; j < 8; ++j) {
                    float2 p = shflx2(v[j], m);
                    float2 o = v[j];
                    v[j].x = ca.x*o.x - ca.y*o.y + cb.x*p.x - cb.y*p.y;
                    v[j].y = ca.x*o.y + ca.y*o.x + cb.x*p.y + cb.y*p.x;
                }
            }
            {   float2 g0 = gg[gb+8][0], g1 = gg[gb+8][1], g2 = gg[gb+8][2], g3 = gg[gb+8][3];
                bfly(g0,g1,g2,g3, v[0], v[4]); bfly(g0,g1,g2,g3, v[1], v[5]);
                bfly(g0,g1,g2,g3, v[2], v[6]); bfly(g0,g1,g2,g3, v[3], v[7]); }
            {   float2 g0 = gg[gb+9][0], g1 = gg[gb+9][1], g2 = gg[gb+9][2], g3 = gg[gb+9][3];
                bfly(g0,g1,g2,g3, v[0], v[2]); bfly(g0,g1,g2,g3, v[1], v[3]);
                bfly(g0,g1,g2,g3, v[4], v[6]); bfly(g0,g1,g2,g3, v[5], v[7]); }
            {   float2 g0 = gg[gb+10][0], g1 = gg[gb+10][1], g2 = gg[gb+10][2], g3 = gg[gb+10][3];
                bfly(g0,g1,g2,g3, v[0], v[1]); bfly(g0,g1,g2,g3, v[2], v[3]);
                bfly(g0,g1,g2,g3, v[4], v[5]); bfly(g0,g1,g2,g3, v[6], v[7]); }

            if (layer < 4) {
                #pragma unroll
                for (int j = 0; j < 8; ++j) V[sb + j] = v[j];
                __syncthreads();
            } else {
                // direct bf16 store of 8 consecutive elements
                const int base = tid << 3;
                u32x4 pr, pi;
                pr.x = (unsigned)f2bf(v[0].x) | ((unsigned)f2bf(v[1].x) << 16);
                pr.y = (unsigned)f2bf(v[2].x) | ((unsigned)f2bf(v[3].x) << 16);
                pr.z = (unsigned)f2bf(v[4].x) | ((unsigned)f2bf(v[5].x) << 16);
                pr.w = (unsigned)f2bf(v[6].x) | ((unsigned)f2bf(v[7].x) << 16);
                pi.x = (unsigned)f2bf(v[0].y) | ((unsigned)f2bf(v[1].y) << 16);
                pi.y = (unsigned)f2bf(v[2].y) | ((unsigned)f2bf(v[3].y) << 16);
                pi.z = (unsigned)f2bf(v[4].y) | ((unsigned)f2bf(v[5].y) << 16);
                pi.w = (unsigned)f2bf(v[6].y) | ((unsigned)f2bf(v[7].y) << 16);
                *(u32x4*)(ut_re + (size_t)col * DIM + base) = pr;
                *(u32x4*)(ut_im + (size_t)col * DIM + base) = pi;
            }
        }
    }
}

// ---------------------------------------------------------------------------
// Kernel 2: bf16 transpose (U^T -> U), 64x64 LDS tiles; z selects re/im.
// ---------------------------------------------------------------------------
__global__ __launch_bounds__(256) void transpose2(const u16* __restrict__ sre,
                                                  const u16* __restrict__ sim,
                                                  u16* __restrict__ dre,
                                                  u16* __restrict__ dim_) {
    const u16* s = blockIdx.z ? sim : sre;
    u16*       d = blockIdx.z ? dim_ : dre;
    __shared__ alignas(16) u16 tile[64][66];
    const int bx = blockIdx.x * 64, by = blockIdx.y * 64;
    for (int e = threadIdx.x; e < 1024; e += 256) {
        int r = e >> 4, c4 = (e & 15) * 4;
        uint2 v = *(const uint2*)(s + (size_t)(by + r) * DIM + bx + c4);
        u16* tp = &tile[r][c4];
        tp[0] = (u16)(v.x); tp[1] = (u16)(v.x >> 16);
        tp[2] = (u16)(v.y); tp[3] = (u16)(v.y >> 16);
    }
    __syncthreads();
    for (int e = threadIdx.x; e < 1024; e += 256) {
        int r = e >> 4, c4 = (e & 15) * 4;
        unsigned lo = (unsigned)tile[c4][r]     | ((unsigned)tile[c4+1][r] << 16);
        unsigned hi = (unsigned)tile[c4+2][r]   | ((unsigned)tile[c4+3][r] << 16);
        *(uint2*)(d + (size_t)(bx + r) * DIM + by + c4) = make_uint2(lo, hi);
    }
}

// ---------------------------------------------------------------------------
// Kernel 2b: X (fp32) -> bf16 plane, once.
// ---------------------------------------------------------------------------
__global__ __launch_bounds__(256) void x2bf(const float* __restrict__ x,
                                            u16* __restrict__ xb) {
    const int i = (blockIdx.x * 256 + threadIdx.x) * 8;
    const float4* s = (const float4*)(x + i);
    float4 v0 = s[0], v1 = s[1];
    u32x4 pk;
    pk.x = (unsigned)f2bf(v0.x) | ((unsigned)f2bf(v0.y) << 16);
    pk.y = (unsigned)f2bf(v0.z) | ((unsigned)f2bf(v0.w) << 16);
    pk.z = (unsigned)f2bf(v1.x) | ((unsigned)f2bf(v1.y) << 16);
    pk.w = (unsigned)f2bf(v1.z) | ((unsigned)f2bf(v1.w) << 16);
    *(u32x4*)(xb + i) = pk;
}

// ---------------------------------------------------------------------------
// GEMM stage 1 (MFMA, PRODUCT-SPLIT, 128x128, BK=64 two-panel, double-buf):
// z=0: pt = Ure X^T; z=1: qt = Uim X^T.  B pre-converted bf16 (xb).
// ---------------------------------------------------------------------------
__global__ __launch_bounds__(256, 2) void gemm_stage1(
        const u16* __restrict__ ure, const u16* __restrict__ uim,
        const u16* __restrict__ xb,
        u16* __restrict__ pt, u16* __restrict__ qt) {
    __shared__ alignas(16) u16 Ab[2][2][128*32], Bx[2][2][128*32]; // [buf][panel]
    const u16* A  = blockIdx.z ? uim : ure;
    u16*      dst = blockIdx.z ? qt  : pt;
    const int tid  = threadIdx.x;
    const int lane = tid & 63, w = tid >> 6;
    const int m0 = blockIdx.y * 128, n0 = blockIdx.x * 128;
    const int wm = (w >> 1) * 64, wn = (w & 1) * 64;
    const int ml = lane & 15, quad = lane >> 4;

    f32x4 acc[4][4];
    #pragma unroll
    for (int i = 0; i < 4; ++i)
        #pragma unroll
        for (int j = 0; j < 4; ++j) {
            f32x4 z = {0.f, 0.f, 0.f, 0.f};
            acc[i][j] = z;
        }

    auto stage = [&](int b, int k0) {   // stages both 32-col panels (64 cols)
        #pragma unroll
        for (int pn = 0; pn < 2; ++pn) {
            #pragma unroll
            for (int t = 0; t < 2; ++t) {
                int ci = t * 256 + tid;          // 16B chunk = 8 bf16
                int r = ci >> 2, c = ci & 3;
                size_t goA = ((size_t)(m0 + r) * DIM + k0 + pn * 32) * 2 + c * 16;
                size_t goB = ((size_t)(n0 + r) * DIM + k0 + pn * 32) * 2 + c * 16;
                gl_lds16((const char*)A  + goA, (char*)Ab[b][pn] + ci * 16);
                gl_lds16((const char*)xb + goB, (char*)Bx[b][pn] + ci * 16);
            }
        }
    };

    stage(0, 0);
    __syncthreads();

    for (int k0 = 0; k0 < DIM; k0 += 64) {
        const int cb = (k0 >> 6) & 1;
        if (k0 + 64 < DIM) stage(cb ^ 1, k0 + 64);   // prefetch next 64-col tile

        #pragma unroll
        for (int pn = 0; pn < 2; ++pn) {
            bf16x8 af[4], bf[4];
            #pragma unroll
            for (int i = 0; i < 4; ++i) {
                af[i] = *(const bf16x8*)(Ab[cb][pn] + (wm + i*16 + ml) * 32 + quad * 8);
                bf[i] = *(const bf16x8*)(Bx[cb][pn] + (wn + i*16 + ml) * 32 + quad * 8);
            }
            #pragma unroll
            for (int i = 0; i < 4; ++i)
                #pragma unroll
                for (int j = 0; j < 4; ++j)
                    acc[i][j] = __builtin_amdgcn_mfma_f32_16x16x32_bf16(af[i], bf[j], acc[i][j], 0, 0, 0);
        }
        __syncthreads();
    }
    // C/D layout: col = lane&15, row = quad*4 + reg
    #pragma unroll
    for (int i = 0; i < 4; ++i)
        #pragma unroll
        for (int j = 0; j < 4; ++j) {
            int row = m0 + wm + i*16 + quad*4;
            int col = n0 + wn + j*16 + ml;
            #pragma unroll
            for (int r = 0; r < 4; ++r)
                dst[(size_t)(row + r) * DIM + col] = f2bf(acc[i][j][r]);
        }
}

// ---------------------------------------------------------------------------
// GEMM stage 2 FUSED (single dispatch, K=4096 over both planes):
// out = Ure X Ure^T + Uim X Uim^T = Re(U X U^H), register accumulation,
// plain fp32 store -- no memset, no atomics.
// ---------------------------------------------------------------------------
__global__ __launch_bounds__(256, 2) void gemm_stage2_fused(
        const u16* __restrict__ ure, const u16* __restrict__ uim,
        const u16* __restrict__ pt, const u16* __restrict__ qt,
        float* __restrict__ out) {
    __shared__ alignas(16) u16 Ab[2][2][128*32], Bb[2][2][128*32];
    const int tid  = threadIdx.x;
    const int lane = tid & 63, w = tid >> 6;
    const int m0 = blockIdx.y * 128, n0 = blockIdx.x * 128;
    const int wm = (w >> 1) * 64, wn = (w & 1) * 64;
    const int ml = lane & 15, quad = lane >> 4;

    f32x4 acc[4][4];
    #pragma unroll
    for (int i = 0; i < 4; ++i)
        #pragma unroll
        for (int j = 0; j < 4; ++j) {
            f32x4 z = {0.f, 0.f, 0.f, 0.f};
            acc[i][j] = z;
        }

    auto stage = [&](int b, int kk) {            // kk in [0, 4096)
        const u16* A = (kk & DIM) ? uim : ure;
        const u16* B = (kk & DIM) ? qt  : pt;
        const int k0 = kk & (DIM - 1);
        #pragma unroll
        for (int pn = 0; pn < 2; ++pn) {
            #pragma unroll
            for (int t = 0; t < 2; ++t) {
                int ci = t * 256 + tid;
                int r = ci >> 2, c = ci & 3;
                size_t goA = ((size_t)(m0 + r) * DIM + k0 + pn * 32) * 2 + c * 16;
                size_t goB = ((size_t)(n0 + r) * DIM + k0 + pn * 32) * 2 + c * 16;
                gl_lds16((const char*)A + goA, (char*)Ab[b][pn] + ci * 16);
                gl_lds16((const char*)B + goB, (char*)Bb[b][pn] + ci * 16);
            }
        }
    };

    stage(0, 0);
    __syncthreads();

    for (int kk = 0; kk < 2 * DIM; kk += 64) {
        const int cb = (kk >> 6) & 1;
        if (kk + 64 < 2 * DIM) stage(cb ^ 1, kk + 64);

        #pragma unroll
        for (int pn = 0; pn < 2; ++pn) {
            bf16x8 af[4], bf[4];
            #pragma unroll
            for (int i = 0; i < 4; ++i) {
                af[i] = *(const bf16x8*)(Ab[cb][pn] + (wm + i*16 + ml) * 32 + quad * 8);
                bf[i] = *(const bf16x8*)(Bb[cb][pn] + (wn + i*16 + ml) * 32 + quad * 8);
            }
            #pragma unroll
            for (int i = 0; i < 4; ++i)
                #pragma unroll
                for (int j = 0; j < 4; ++j)
                    acc[i][j] = __builtin_amdgcn_mfma_f32_16x16x32_bf16(af[i], bf[j], acc[i][j], 0, 0, 0);
        }
        __syncthreads();
    }
    #pragma unroll
    for (int i = 0; i < 4; ++i)
        #pragma unroll
        for (int j = 0; j < 4; ++j) {
            int row = m0 + wm + i*16 + quad*4;
            int col = n0 + wn + j*16 + ml;
            #pragma unroll
            for (int r = 0; r < 4; ++r)
                out[(size_t)(row + r) * DIM + col] = acc[i][j][r];
        }
}

// ---------------------------------------------------------------------------
// Fallback (complex interleaved output) — insurance only, 128x128 1-buf LDS.
// ---------------------------------------------------------------------------
__global__ __launch_bounds__(256, 1) void gemm_stage2_cplx(
        const u16* __restrict__ ure, const u16* __restrict__ uim,
        const u16* __restrict__ pt, const u16* __restrict__ qt,
        float2* __restrict__ out, size_t out_lim) {
    __shared__ alignas(16) u16 Ar[128*32], Ai[128*32], Bp[128*32], Bq[128*32];
    const int tid  = threadIdx.x;
    const int lane = tid & 63, w = tid >> 6;
    const int m0 = blockIdx.y * 128, n0 = blockIdx.x * 128;
    const int wm = (w >> 1) * 64, wn = (w & 1) * 64;
    const int ml = lane & 15, quad = lane >> 4;

    f32x4 accR[4][4], accI[4][4];
    #pragma unroll
    for (int i = 0; i < 4; ++i)
        #pragma unroll
        for (int j = 0; j < 4; ++j) {
            f32x4 z = {0.f, 0.f, 0.f, 0.f};
            accR[i][j] = z; accI[i][j] = z;
        }

    for (int k0 = 0; k0 < DIM; k0 += 32) {
        #pragma unroll
        for (int t = 0; t < 2; ++t) {
            int ci = t * 256 + tid;
            int r = ci >> 2, c = ci & 3;
            size_t goA = ((size_t)(m0 + r) * DIM + k0) * 2 + c * 16;
            size_t goB = ((size_t)(n0 + r) * DIM + k0) * 2 + c * 16;
            gl_lds16((const char*)ure + goA, (char*)Ar + ci * 16);
            gl_lds16((const char*)uim + goA, (char*)Ai + ci * 16);
            gl_lds16((const char*)pt  + goB, (char*)Bp + ci * 16);
            gl_lds16((const char*)qt  + goB, (char*)Bq + ci * 16);
        }
        __syncthreads();
        bf16x8 ar[4], ai[4], bp[4], bq[4];
        #pragma unroll
        for (int i = 0; i < 4; ++i) {
            ar[i] = *(const bf16x8*)(Ar + (wm + i*16 + ml) * 32 + quad * 8);
            ai[i] = *(const bf16x8*)(Ai + (wm + i*16 + ml) * 32 + quad * 8);
            bp[i] = *(const bf16x8*)(Bp + (wn + i*16 + ml) * 32 + quad * 8);
            bq[i] = *(const bf16x8*)(Bq + (wn + i*16 + ml) * 32 + quad * 8);
        }
        #pragma unroll
        for (int i = 0; i < 4; ++i)
            #pragma unroll
            for (int j = 0; j < 4; ++j) {
                accR[i][j] = __builtin_amdgcn_mfma_f32_16x16x32_bf16(ar[i], bp[j], accR[i][j], 0, 0, 0);
                accR[i][j] = __builtin_amdgcn_mfma_f32_16x16x32_bf16(ai[i], bq[j], accR[i][j], 0, 0, 0);
                accI[i][j] = __builtin_amdgcn_mfma_f32_16x16x32_bf16(ai[i], bp[j], accI[i][j], 0, 0, 0);
                f32x4 t2 = __builtin_amdgcn_mfma_f32_16x16x32_bf16(ar[i], bq[j], {0.f,0.f,0.f,0.f}, 0, 0, 0);
                accI[i][j] -= t2;
            }
        __syncthreads();
    }
    #pragma unroll
    for (int i = 0; i < 4; ++i)
        #pragma unroll
        for (int j = 0; j < 4; ++j) {
            int row = m0 + wm + i*16 + quad*4;
            int col = n0 + wn + j*16 + ml;
            #pragma unroll
            for (int r = 0; r < 4; ++r) {
                size_t idx = (size_t)(row + r) * DIM + col;
                if (idx < out_lim)
                    out[idx] = make_float2(accR[i][j][r], accI[i][j][r]);
            }
        }
}

// ---------------------------------------------------------------------------
extern "C" void kernel_launch(void* const* d_in, const int* in_sizes, int n_in,
                              void* d_out, int out_size, void* d_ws, size_t ws_size,
                              hipStream_t stream) {
    int xi = (in_sizes[0] >= in_sizes[1]) ? 0 : 1;
    const float* x = (const float*)d_in[xi];
    const float* w = (const float*)d_in[1 - xi];

    char* ws = (char*)d_ws;
    const size_t P = (size_t)DIM * DIM * 2;   // one bf16 plane = 8 MiB
    if (ws_size < 4 * P) return;

    u16* ut_re = (u16*)(ws);
    u16* ut_im = (u16*)(ws + P);
    u16* u_re  = (u16*)(ws + 2*P);
    u16* u_im  = (u16*)(ws + 3*P);
    u16* pt    = ut_re;   // reuse after transpose
    u16* qt    = ut_im;
    // bf16 X plane: ws plane 5 if it fits, else d_out's first 8 MiB
    // (d_out is dead until after gemm_stage1 in both output paths).
    u16* xb = (ws_size >= 5 * P) ? (u16*)(ws + 4*P) : (u16*)d_out;

    build_ut<<<DIM, 256, 0, stream>>>(w, ut_re, ut_im);
    transpose2<<<dim3(32, 32, 2), 256, 0, stream>>>(ut_re, ut_im, u_re, u_im);
    x2bf<<<DIM*DIM/(256*8), 256, 0, stream>>>(x, xb);
    gemm_stage1<<<dim3(16, 16, 2), 256, 0, stream>>>(u_re, u_im, xb, pt, qt);

    if (out_size == DIM * DIM) {
        gemm_stage2_fused<<<dim3(16, 16), 256, 0, stream>>>(u_re, u_im, pt, qt,
                                                            (float*)d_out);
    } else {
        gemm_stage2_cplx<<<dim3(16, 16), 256, 0, stream>>>(u_re, u_im, pt, qt,
                                                           (float2*)d_out,
                                                           (size_t)out_size / 2);
    }
}

// Round 3
// 245.767 us; speedup vs baseline: 1.0153x; 1.0153x over previous
//
#include <hip/hip_runtime.h>

typedef unsigned short u16;
typedef __attribute__((ext_vector_type(8))) short bf16x8;   // 8 bf16 in 4 VGPRs
typedef __attribute__((ext_vector_type(4))) float f32x4;
typedef __attribute__((ext_vector_type(4))) unsigned int u32x4;

#define DIM 2048

__device__ inline u16 f2bf(float f) {
    unsigned u = __builtin_bit_cast(unsigned, f);
    u = (u + 0x7FFFu + ((u >> 16) & 1u)) >> 16;   // RNE, finite inputs only
    return (u16)u;
}

__device__ inline void gl_lds16(const void* g, void* l) {
    __builtin_amdgcn_global_load_lds(
        (const __attribute__((address_space(1))) unsigned int*)g,
        (__attribute__((address_space(3))) unsigned int*)l, 16, 0, 0);
}

struct c32 { float x, y; };
__device__ inline c32 cmul(c32 a, c32 b) { return {a.x*b.x - a.y*b.y, a.x*b.y + a.y*b.x}; }
__device__ inline float2 cmulf2(float2 a, float2 b) {
    return make_float2(a.x*b.x - a.y*b.y, a.x*b.y + a.y*b.x);
}

__device__ inline int slot2(int i) { return i + (i >> 4); }   // float2 bank-pad

// exact xor-lane swizzle for mask < 32 (BitMode, per-32-lane halves; xor
// mask<32 never crosses the half boundary, so valid on wave64)
template<int M>
__device__ inline float2 swzx2(float2 v) {
    int x = __builtin_amdgcn_ds_swizzle(__builtin_bit_cast(int, v.x), (M << 10) | 0x1F);
    int y = __builtin_amdgcn_ds_swizzle(__builtin_bit_cast(int, v.y), (M << 10) | 0x1F);
    return make_float2(__builtin_bit_cast(float, x), __builtin_bit_cast(float, y));
}

// complex butterfly: (u,w) <- (g0*u + g1*w, g2*u + g3*w)
__device__ inline void bfly(float2 g0, float2 g1, float2 g2, float2 g3,
                            float2& u, float2& w) {
    float2 nu, nw;
    nu.x = g0.x*u.x - g0.y*u.y + g1.x*w.x - g1.y*w.y;
    nu.y = g0.x*u.y + g0.y*u.x + g1.x*w.y + g1.y*w.x;
    nw.x = g2.x*u.x - g2.y*u.y + g3.x*w.x - g3.y*w.y;
    nw.y = g2.x*u.y + g2.y*u.x + g3.x*w.y + g3.y*w.x;
    u = nu; w = nw;
}

// ---------------------------------------------------------------------------
// Kernel 1: build T = U^T, one column per block, statevector in LDS (float2).
// Round-16 structure (ping-pong V, 2 barriers/layer):
//  - Layer 0: direct Kronecker product into registers -> V[0] home layout
//    (thread t owns elements t*8..t*8+7).
//  - Per layer 1..4 (cur toggles):
//      Pass A: perm-read V[cur] (ring perm closed form
//              pe=(e^(e>>1))^((e&1)?0x600:0), validated r6-r15), gates on
//              bits 10,9,8 in registers, write V[cur^1] home.  No read-fence
//              barrier needed (writes go to the other buffer).
//      Pass B: read own 8 consecutive elements of V[cur^1]; gates on bits
//              7..3 via ds_swizzle (masks 16,8,4,2,1); gates on bits 2..0 in
//              registers; write own slots in place (no internal barrier).
//    Layer 4's Pass B stores bf16 directly to global.
//  - Barriers: 13 -> 9.  LDS: 36.6 KB -> 4 blocks/CU.
// ---------------------------------------------------------------------------
__global__ __launch_bounds__(256) void build_ut(const float* __restrict__ w,
                                                u16* __restrict__ ut_re,
                                                u16* __restrict__ ut_im) {
    __shared__ alignas(16) float2 gg[55][4];             // 2x2 gates, row-major
    __shared__ alignas(16) float2 V[2][DIM + (DIM >> 4)];
    const int tid  = threadIdx.x;
    const int lane = tid & 63;
    const int col  = blockIdx.x;

    if (tid < 55) {
        const int layer = tid / 11, q = tid - layer * 11;
        const float WM = 0.63245553203367586f;   // sqrt(2)*5^-0.5
        float hx = 0.5f * WM * w[33*layer + q];
        float hy = 0.5f * WM * w[33*layer + 11 + q];
        float hz = 0.5f * WM * w[33*layer + 22 + q];
        float cx = cosf(hx), sx = sinf(hx);
        float cy = cosf(hy), sy = sinf(hy);
        float cz = cosf(hz), sz = sinf(hz);
        c32 m00{cy*cx,  sy*sx}, m01{-sy*cx, -cy*sx};
        c32 m10{sy*cx, -cy*sx}, m11{ cy*cx, -sy*sx};
        c32 em{cz, -sz}, ep{cz, sz};
        c32 r0 = cmul(em, m00), r1 = cmul(em, m01);
        c32 r2 = cmul(ep, m10), r3 = cmul(ep, m11);
        gg[tid][0] = make_float2(r0.x, r0.y);
        gg[tid][1] = make_float2(r1.x, r1.y);
        gg[tid][2] = make_float2(r2.x, r2.y);
        gg[tid][3] = make_float2(r3.x, r3.y);
    }
    __syncthreads();

    // --- Layer 0: direct Kronecker product of a basis vector (registers) --
    {
        float2 p = gg[0][((((tid >> 7) & 1) << 1)) | ((col >> 10) & 1)];
        #pragma unroll
        for (int b = 9; b >= 3; --b) {
            float2 ge = gg[10 - b][(((tid >> (b - 3)) & 1) << 1) | ((col >> b) & 1)];
            p = cmulf2(p, ge);
        }
        const int c2 = (col >> 2) & 1, c1 = (col >> 1) & 1, c0 = col & 1;
        float2 a0  = cmulf2(p, gg[8][c2]);       // bit2 = 0
        float2 a1  = cmulf2(p, gg[8][2 | c2]);   // bit2 = 1
        float2 b00 = cmulf2(a0, gg[9][c1]);
        float2 b01 = cmulf2(a0, gg[9][2 | c1]);
        float2 b10 = cmulf2(a1, gg[9][c1]);
        float2 b11 = cmulf2(a1, gg[9][2 | c1]);
        float2 g0 = gg[10][c0], g1 = gg[10][2 | c0];
        const int sb = slot2(tid << 3);           // 8 consecutive slots
        V[0][sb + 0] = cmulf2(b00, g0);
        V[0][sb + 1] = cmulf2(b00, g1);
        V[0][sb + 2] = cmulf2(b01, g0);
        V[0][sb + 3] = cmulf2(b01, g1);
        V[0][sb + 4] = cmulf2(b10, g0);
        V[0][sb + 5] = cmulf2(b10, g1);
        V[0][sb + 6] = cmulf2(b11, g0);
        V[0][sb + 7] = cmulf2(b11, g1);
    }
    __syncthreads();

    int cur = 0;
    for (int layer = 1; layer < 5; ++layer) {
        const int gb = layer * 11;

        // ---- Pass A: bits {10,9,8}; ring perm on read; write other buf ----
        {
            float2 a[8]; int sl[8];
            #pragma unroll
            for (int j = 0; j < 8; ++j) {
                int e  = tid | (j << 8);                 // j0->bit8 j1->bit9 j2->bit10
                sl[j]  = slot2(e);
                int pe = (e ^ (e >> 1)) ^ ((e & 1) ? 0x600 : 0);
                a[j]   = V[cur][slot2(pe)];
            }
            {   float2 g0 = gg[gb+0][0], g1 = gg[gb+0][1], g2 = gg[gb+0][2], g3 = gg[gb+0][3];
                bfly(g0,g1,g2,g3, a[0], a[4]); bfly(g0,g1,g2,g3, a[1], a[5]);
                bfly(g0,g1,g2,g3, a[2], a[6]); bfly(g0,g1,g2,g3, a[3], a[7]); }
            {   float2 g0 = gg[gb+1][0], g1 = gg[gb+1][1], g2 = gg[gb+1][2], g3 = gg[gb+1][3];
                bfly(g0,g1,g2,g3, a[0], a[2]); bfly(g0,g1,g2,g3, a[1], a[3]);
                bfly(g0,g1,g2,g3, a[4], a[6]); bfly(g0,g1,g2,g3, a[5], a[7]); }
            {   float2 g0 = gg[gb+2][0], g1 = gg[gb+2][1], g2 = gg[gb+2][2], g3 = gg[gb+2][3];
                bfly(g0,g1,g2,g3, a[0], a[1]); bfly(g0,g1,g2,g3, a[2], a[3]);
                bfly(g0,g1,g2,g3, a[4], a[5]); bfly(g0,g1,g2,g3, a[6], a[7]); }
            #pragma unroll
            for (int j = 0; j < 8; ++j) V[cur ^ 1][sl[j]] = a[j];
            __syncthreads();
        }

        // ---- Pass B: home layout; bits 7..3 by ds_swizzle, 2..0 in reg ----
        {
            const int sb = slot2(tid << 3);
            float2 v[8];
            #pragma unroll
            for (int j = 0; j < 8; ++j) v[j] = V[cur ^ 1][sb + j];

            // gate on element-bit b via lane-xor mask M = 1<<(b-3)
            auto lane_gate = [&](int gq, int M, auto swz) {
                const bool hi = (lane & M) != 0;
                float2 g0 = gg[gq][0], g1 = gg[gq][1], g2 = gg[gq][2], g3 = gg[gq][3];
                float2 ca = hi ? g3 : g0;                // x own
                float2 cb = hi ? g2 : g1;                // x partner
                #pragma unroll
                for (int j = 0; j < 8; ++j) {
                    float2 p = swz(v[j]);
                    float2 o = v[j];
                    v[j].x = ca.x*o.x - ca.y*o.y + cb.x*p.x - cb.y*p.y;
                    v[j].y = ca.x*o.y + ca.y*o.x + cb.x*p.y + cb.y*p.x;
                }
            };
            lane_gate(gb + 3, 16, [](float2 t){ return swzx2<16>(t); });  // bit 7
            lane_gate(gb + 4,  8, [](float2 t){ return swzx2< 8>(t); });  // bit 6
            lane_gate(gb + 5,  4, [](float2 t){ return swzx2< 4>(t); });  // bit 5
            lane_gate(gb + 6,  2, [](float2 t){ return swzx2< 2>(t); });  // bit 4
            lane_gate(gb + 7,  1, [](float2 t){ return swzx2< 1>(t); });  // bit 3

            {   float2 g0 = gg[gb+8][0], g1 = gg[gb+8][1], g2 = gg[gb+8][2], g3 = gg[gb+8][3];
                bfly(g0,g1,g2,g3, v[0], v[4]); bfly(g0,g1,g2,g3, v[1], v[5]);
                bfly(g0,g1,g2,g3, v[2], v[6]); bfly(g0,g1,g2,g3, v[3], v[7]); }
            {   float2 g0 = gg[gb+9][0], g1 = gg[gb+9][1], g2 = gg[gb+9][2], g3 = gg[gb+9][3];
                bfly(g0,g1,g2,g3, v[0], v[2]); bfly(g0,g1,g2,g3, v[1], v[3]);
                bfly(g0,g1,g2,g3, v[4], v[6]); bfly(g0,g1,g2,g3, v[5], v[7]); }
            {   float2 g0 = gg[gb+10][0], g1 = gg[gb+10][1], g2 = gg[gb+10][2], g3 = gg[gb+10][3];
                bfly(g0,g1,g2,g3, v[0], v[1]); bfly(g0,g1,g2,g3, v[2], v[3]);
                bfly(g0,g1,g2,g3, v[4], v[5]); bfly(g0,g1,g2,g3, v[6], v[7]); }

            if (layer < 4) {
                #pragma unroll
                for (int j = 0; j < 8; ++j) V[cur ^ 1][sb + j] = v[j];
                __syncthreads();
            } else {
                // direct bf16 store of 8 consecutive elements
                const int base = tid << 3;
                u32x4 pr, pi;
                pr.x = (unsigned)f2bf(v[0].x) | ((unsigned)f2bf(v[1].x) << 16);
                pr.y = (unsigned)f2bf(v[2].x) | ((unsigned)f2bf(v[3].x) << 16);
                pr.z = (unsigned)f2bf(v[4].x) | ((unsigned)f2bf(v[5].x) << 16);
                pr.w = (unsigned)f2bf(v[6].x) | ((unsigned)f2bf(v[7].x) << 16);
                pi.x = (unsigned)f2bf(v[0].y) | ((unsigned)f2bf(v[1].y) << 16);
                pi.y = (unsigned)f2bf(v[2].y) | ((unsigned)f2bf(v[3].y) << 16);
                pi.z = (unsigned)f2bf(v[4].y) | ((unsigned)f2bf(v[5].y) << 16);
                pi.w = (unsigned)f2bf(v[6].y) | ((unsigned)f2bf(v[7].y) << 16);
                *(u32x4*)(ut_re + (size_t)col * DIM + base) = pr;
                *(u32x4*)(ut_im + (size_t)col * DIM + base) = pi;
            }
        }
        cur ^= 1;
    }
}

// ---------------------------------------------------------------------------
// Kernel 2: bf16 transpose (U^T -> U), 64x64 LDS tiles; z selects re/im.
// ---------------------------------------------------------------------------
__global__ __launch_bounds__(256) void transpose2(const u16* __restrict__ sre,
                                                  const u16* __restrict__ sim,
                                                  u16* __restrict__ dre,
                                                  u16* __restrict__ dim_) {
    const u16* s = blockIdx.z ? sim : sre;
    u16*       d = blockIdx.z ? dim_ : dre;
    __shared__ alignas(16) u16 tile[64][66];
    const int bx = blockIdx.x * 64, by = blockIdx.y * 64;
    for (int e = threadIdx.x; e < 1024; e += 256) {
        int r = e >> 4, c4 = (e & 15) * 4;
        uint2 v = *(const uint2*)(s + (size_t)(by + r) * DIM + bx + c4);
        u16* tp = &tile[r][c4];
        tp[0] = (u16)(v.x); tp[1] = (u16)(v.x >> 16);
        tp[2] = (u16)(v.y); tp[3] = (u16)(v.y >> 16);
    }
    __syncthreads();
    for (int e = threadIdx.x; e < 1024; e += 256) {
        int r = e >> 4, c4 = (e & 15) * 4;
        unsigned lo = (unsigned)tile[c4][r]     | ((unsigned)tile[c4+1][r] << 16);
        unsigned hi = (unsigned)tile[c4+2][r]   | ((unsigned)tile[c4+3][r] << 16);
        *(uint2*)(d + (size_t)(bx + r) * DIM + by + c4) = make_uint2(lo, hi);
    }
}

// ---------------------------------------------------------------------------
// Kernel 2b: X (fp32) -> bf16 plane, once.
// ---------------------------------------------------------------------------
__global__ __launch_bounds__(256) void x2bf(const float* __restrict__ x,
                                            u16* __restrict__ xb) {
    const int i = (blockIdx.x * 256 + threadIdx.x) * 8;
    const float4* s = (const float4*)(x + i);
    float4 v0 = s[0], v1 = s[1];
    u32x4 pk;
    pk.x = (unsigned)f2bf(v0.x) | ((unsigned)f2bf(v0.y) << 16);
    pk.y = (unsigned)f2bf(v0.z) | ((unsigned)f2bf(v0.w) << 16);
    pk.z = (unsigned)f2bf(v1.x) | ((unsigned)f2bf(v1.y) << 16);
    pk.w = (unsigned)f2bf(v1.z) | ((unsigned)f2bf(v1.w) << 16);
    *(u32x4*)(xb + i) = pk;
}

// ---------------------------------------------------------------------------
// GEMM stage 1 FUSED (single dispatch, stacked planes, 128x128, BK=64
// two-panel, double-buf): rows 0..2047 = Ure, 2048..4095 = Uim (contiguous
// workspace planes); dst rows likewise pt then qt.  [pt;qt] = [Ure;Uim] X^T.
// ---------------------------------------------------------------------------
__global__ __launch_bounds__(256, 2) void gemm_stage1(
        const u16* __restrict__ uStack,      // u_re base (u_im contiguous after)
        const u16* __restrict__ xb,
        u16* __restrict__ ptStack) {         // pt base (qt contiguous after)
    __shared__ alignas(16) u16 Ab[2][2][128*32], Bx[2][2][128*32]; // [buf][panel]
    const int tid  = threadIdx.x;
    const int lane = tid & 63, w = tid >> 6;
    const int m0 = blockIdx.y * 128, n0 = blockIdx.x * 128;   // m0 in [0,4096)
    const int wm = (w >> 1) * 64, wn = (w & 1) * 64;
    const int ml = lane & 15, quad = lane >> 4;

    f32x4 acc[4][4];
    #pragma unroll
    for (int i = 0; i < 4; ++i)
        #pragma unroll
        for (int j = 0; j < 4; ++j) {
            f32x4 z = {0.f, 0.f, 0.f, 0.f};
            acc[i][j] = z;
        }

    auto stage = [&](int b, int k0) {   // stages both 32-col panels (64 cols)
        #pragma unroll
        for (int pn = 0; pn < 2; ++pn) {
            #pragma unroll
            for (int t = 0; t < 2; ++t) {
                int ci = t * 256 + tid;          // 16B chunk = 8 bf16
                int r = ci >> 2, c = ci & 3;
                size_t goA = ((size_t)(m0 + r) * DIM + k0 + pn * 32) * 2 + c * 16;
                size_t goB = ((size_t)(n0 + r) * DIM + k0 + pn * 32) * 2 + c * 16;
                gl_lds16((const char*)uStack + goA, (char*)Ab[b][pn] + ci * 16);
                gl_lds16((const char*)xb     + goB, (char*)Bx[b][pn] + ci * 16);
            }
        }
    };

    stage(0, 0);
    __syncthreads();

    for (int k0 = 0; k0 < DIM; k0 += 64) {
        const int cb = (k0 >> 6) & 1;
        if (k0 + 64 < DIM) stage(cb ^ 1, k0 + 64);   // prefetch next 64-col tile

        #pragma unroll
        for (int pn = 0; pn < 2; ++pn) {
            bf16x8 af[4], bf[4];
            #pragma unroll
            for (int i = 0; i < 4; ++i) {
                af[i] = *(const bf16x8*)(Ab[cb][pn] + (wm + i*16 + ml) * 32 + quad * 8);
                bf[i] = *(const bf16x8*)(Bx[cb][pn] + (wn + i*16 + ml) * 32 + quad * 8);
            }
            #pragma unroll
            for (int i = 0; i < 4; ++i)
                #pragma unroll
                for (int j = 0; j < 4; ++j)
                    acc[i][j] = __builtin_amdgcn_mfma_f32_16x16x32_bf16(af[i], bf[j], acc[i][j], 0, 0, 0);
        }
        __syncthreads();
    }
    // C/D layout: col = lane&15, row = quad*4 + reg
    #pragma unroll
    for (int i = 0; i < 4; ++i)
        #pragma unroll
        for (int j = 0; j < 4; ++j) {
            int row = m0 + wm + i*16 + quad*4;
            int col = n0 + wn + j*16 + ml;
            #pragma unroll
            for (int r = 0; r < 4; ++r)
                ptStack[(size_t)(row + r) * DIM + col] = f2bf(acc[i][j][r]);
        }
}

// ---------------------------------------------------------------------------
// GEMM stage 2 FUSED (single dispatch, K=4096 over both planes):
// out = Ure X Ure^T + Uim X Uim^T = Re(U X U^H), register accumulation,
// plain fp32 store -- no memset, no atomics.
// ---------------------------------------------------------------------------
__global__ __launch_bounds__(256, 2) void gemm_stage2_fused(
        const u16* __restrict__ ure, const u16* __restrict__ uim,
        const u16* __restrict__ pt, const u16* __restrict__ qt,
        float* __restrict__ out) {
    __shared__ alignas(16) u16 Ab[2][2][128*32], Bb[2][2][128*32];
    const int tid  = threadIdx.x;
    const int lane = tid & 63, w = tid >> 6;
    const int m0 = blockIdx.y * 128, n0 = blockIdx.x * 128;
    const int wm = (w >> 1) * 64, wn = (w & 1) * 64;
    const int ml = lane & 15, quad = lane >> 4;

    f32x4 acc[4][4];
    #pragma unroll
    for (int i = 0; i < 4; ++i)
        #pragma unroll
        for (int j = 0; j < 4; ++j) {
            f32x4 z = {0.f, 0.f, 0.f, 0.f};
            acc[i][j] = z;
        }

    auto stage = [&](int b, int kk) {            // kk in [0, 4096)
        const u16* A = (kk & DIM) ? uim : ure;
        const u16* B = (kk & DIM) ? qt  : pt;
        const int k0 = kk & (DIM - 1);
        #pragma unroll
        for (int pn = 0; pn < 2; ++pn) {
            #pragma unroll
            for (int t = 0; t < 2; ++t) {
                int ci = t * 256 + tid;
                int r = ci >> 2, c = ci & 3;
                size_t goA = ((size_t)(m0 + r) * DIM + k0 + pn * 32) * 2 + c * 16;
                size_t goB = ((size_t)(n0 + r) * DIM + k0 + pn * 32) * 2 + c * 16;
                gl_lds16((const char*)A + goA, (char*)Ab[b][pn] + ci * 16);
                gl_lds16((const char*)B + goB, (char*)Bb[b][pn] + ci * 16);
            }
        }
    };

    stage(0, 0);
    __syncthreads();

    for (int kk = 0; kk < 2 * DIM; kk += 64) {
        const int cb = (kk >> 6) & 1;
        if (kk + 64 < 2 * DIM) stage(cb ^ 1, kk + 64);

        #pragma unroll
        for (int pn = 0; pn < 2; ++pn) {
            bf16x8 af[4], bf[4];
            #pragma unroll
            for (int i = 0; i < 4; ++i) {
                af[i] = *(const bf16x8*)(Ab[cb][pn] + (wm + i*16 + ml) * 32 + quad * 8);
                bf[i] = *(const bf16x8*)(Bb[cb][pn] + (wn + i*16 + ml) * 32 + quad * 8);
            }
            #pragma unroll
            for (int i = 0; i < 4; ++i)
                #pragma unroll
                for (int j = 0; j < 4; ++j)
                    acc[i][j] = __builtin_amdgcn_mfma_f32_16x16x32_bf16(af[i], bf[j], acc[i][j], 0, 0, 0);
        }
        __syncthreads();
    }
    #pragma unroll
    for (int i = 0; i < 4; ++i)
        #pragma unroll
        for (int j = 0; j < 4; ++j) {
            int row = m0 + wm + i*16 + quad*4;
            int col = n0 + wn + j*16 + ml;
            #pragma unroll
            for (int r = 0; r < 4; ++r)
                out[(size_t)(row + r) * DIM + col] = acc[i][j][r];
        }
}

// ---------------------------------------------------------------------------
// Fallback (complex interleaved output) — insurance only, 128x128 1-buf LDS.
// ---------------------------------------------------------------------------
__global__ __launch_bounds__(256, 1) void gemm_stage2_cplx(
        const u16* __restrict__ ure, const u16* __restrict__ uim,
        const u16* __restrict__ pt, const u16* __restrict__ qt,
        float2* __restrict__ out, size_t out_lim) {
    __shared__ alignas(16) u16 Ar[128*32], Ai[128*32], Bp[128*32], Bq[128*32];
    const int tid  = threadIdx.x;
    const int lane = tid & 63, w = tid >> 6;
    const int m0 = blockIdx.y * 128, n0 = blockIdx.x * 128;
    const int wm = (w >> 1) * 64, wn = (w & 1) * 64;
    const int ml = lane & 15, quad = lane >> 4;

    f32x4 accR[4][4], accI[4][4];
    #pragma unroll
    for (int i = 0; i < 4; ++i)
        #pragma unroll
        for (int j = 0; j < 4; ++j) {
            f32x4 z = {0.f, 0.f, 0.f, 0.f};
            accR[i][j] = z; accI[i][j] = z;
        }

    for (int k0 = 0; k0 < DIM; k0 += 32) {
        #pragma unroll
        for (int t = 0; t < 2; ++t) {
            int ci = t * 256 + tid;
            int r = ci >> 2, c = ci & 3;
            size_t goA = ((size_t)(m0 + r) * DIM + k0) * 2 + c * 16;
            size_t goB = ((size_t)(n0 + r) * DIM + k0) * 2 + c * 16;
            gl_lds16((const char*)ure + goA, (char*)Ar + ci * 16);
            gl_lds16((const char*)uim + goA, (char*)Ai + ci * 16);
            gl_lds16((const char*)pt  + goB, (char*)Bp + ci * 16);
            gl_lds16((const char*)qt  + goB, (char*)Bq + ci * 16);
        }
        __syncthreads();
        bf16x8 ar[4], ai[4], bp[4], bq[4];
        #pragma unroll
        for (int i = 0; i < 4; ++i) {
            ar[i] = *(const bf16x8*)(Ar + (wm + i*16 + ml) * 32 + quad * 8);
            ai[i] = *(const bf16x8*)(Ai + (wm + i*16 + ml) * 32 + quad * 8);
            bp[i] = *(const bf16x8*)(Bp + (wn + i*16 + ml) * 32 + quad * 8);
            bq[i] = *(const bf16x8*)(Bq + (wn + i*16 + ml) * 32 + quad * 8);
        }
        #pragma unroll
        for (int i = 0; i < 4; ++i)
            #pragma unroll
            for (int j = 0; j < 4; ++j) {
                accR[i][j] = __builtin_amdgcn_mfma_f32_16x16x32_bf16(ar[i], bp[j], accR[i][j], 0, 0, 0);
                accR[i][j] = __builtin_amdgcn_mfma_f32_16x16x32_bf16(ai[i], bq[j], accR[i][j], 0, 0, 0);
                accI[i][j] = __builtin_amdgcn_mfma_f32_16x16x32_bf16(ai[i], bp[j], accI[i][j], 0, 0, 0);
                f32x4 t2 = __builtin_amdgcn_mfma_f32_16x16x32_bf16(ar[i], bq[j], {0.f,0.f,0.f,0.f}, 0, 0, 0);
                accI[i][j] -= t2;
            }
        __syncthreads();
    }
    #pragma unroll
    for (int i = 0; i < 4; ++i)
        #pragma unroll
        for (int j = 0; j < 4; ++j) {
            int row = m0 + wm + i*16 + quad*4;
            int col = n0 + wn + j*16 + ml;
            #pragma unroll
            for (int r = 0; r < 4; ++r) {
                size_t idx = (size_t)(row + r) * DIM + col;
                if (idx < out_lim)
                    out[idx] = make_float2(accR[i][j][r], accI[i][j][r]);
            }
        }
}

// ---------------------------------------------------------------------------
extern "C" void kernel_launch(void* const* d_in, const int* in_sizes, int n_in,
                              void* d_out, int out_size, void* d_ws, size_t ws_size,
                              hipStream_t stream) {
    int xi = (in_sizes[0] >= in_sizes[1]) ? 0 : 1;
    const float* x = (const float*)d_in[xi];
    const float* w = (const float*)d_in[1 - xi];

    char* ws = (char*)d_ws;
    const size_t P = (size_t)DIM * DIM * 2;   // one bf16 plane = 8 MiB
    if (ws_size < 4 * P) return;

    u16* ut_re = (u16*)(ws);
    u16* ut_im = (u16*)(ws + P);
    u16* u_re  = (u16*)(ws + 2*P);
    u16* u_im  = (u16*)(ws + 3*P);
    u16* pt    = ut_re;   // reuse after transpose
    u16* qt    = ut_im;
    // bf16 X plane: ws plane 5 if it fits, else d_out's first 8 MiB
    // (d_out is dead until after gemm_stage1 in both output paths).
    u16* xb = (ws_size >= 5 * P) ? (u16*)(ws + 4*P) : (u16*)d_out;

    build_ut<<<DIM, 256, 0, stream>>>(w, ut_re, ut_im);
    transpose2<<<dim3(32, 32, 2), 256, 0, stream>>>(ut_re, ut_im, u_re, u_im);
    x2bf<<<DIM*DIM/(256*8), 256, 0, stream>>>(x, xb);
    // fused: [pt;qt] = [Ure;Uim] X^T  (stacked 4096-row GEMM, one dispatch)
    gemm_stage1<<<dim3(16, 32), 256, 0, stream>>>(u_re, xb, pt);

    if (out_size == DIM * DIM) {
        gemm_stage2_fused<<<dim3(16, 16), 256, 0, stream>>>(u_re, u_im, pt, qt,
                                                            (float*)d_out);
    } else {
        gemm_stage2_cplx<<<dim3(16, 16), 256, 0, stream>>>(u_re, u_im, pt, qt,
                                                           (float2*)d_out,
                                                           (size_t)out_size / 2);
    }
}

// Round 5
// 239.007 us; speedup vs baseline: 1.0441x; 1.0283x over previous
//
#include <hip/hip_runtime.h>

typedef unsigned short u16;
typedef __attribute__((ext_vector_type(8))) short bf16x8;   // 8 bf16 in 4 VGPRs
typedef __attribute__((ext_vector_type(4))) float f32x4;
typedef __attribute__((ext_vector_type(4))) unsigned int u32x4;

#define DIM 2048

__device__ inline u16 f2bf(float f) {
    unsigned u = __builtin_bit_cast(unsigned, f);
    u = (u + 0x7FFFu + ((u >> 16) & 1u)) >> 16;   // RNE, finite inputs only
    return (u16)u;
}

__device__ inline void gl_lds16(const void* g, void* l) {
    __builtin_amdgcn_global_load_lds(
        (const __attribute__((address_space(1))) unsigned int*)g,
        (__attribute__((address_space(3))) unsigned int*)l, 16, 0, 0);
}

struct c32 { float x, y; };
__device__ inline c32 cmul(c32 a, c32 b) { return {a.x*b.x - a.y*b.y, a.x*b.y + a.y*b.x}; }
__device__ inline float2 cmulf2(float2 a, float2 b) {
    return make_float2(a.x*b.x - a.y*b.y, a.x*b.y + a.y*b.x);
}

__device__ inline int slot2(int i) { return i + (i >> 4); }   // float2 bank-pad

// exact xor-lane swizzle for mask < 32 (BitMode; xor mask<32 never crosses the
// 32-lane half boundary, so valid on wave64).  Validated r16.
template<int M>
__device__ inline float2 swzx2(float2 v) {
    int x = __builtin_amdgcn_ds_swizzle(__builtin_bit_cast(int, v.x), (M << 10) | 0x1F);
    int y = __builtin_amdgcn_ds_swizzle(__builtin_bit_cast(int, v.y), (M << 10) | 0x1F);
    return make_float2(__builtin_bit_cast(float, x), __builtin_bit_cast(float, y));
}

// complex butterfly: (u,w) <- (g0*u + g1*w, g2*u + g3*w)
__device__ inline void bfly(float2 g0, float2 g1, float2 g2, float2 g3,
                            float2& u, float2& w) {
    float2 nu, nw;
    nu.x = g0.x*u.x - g0.y*u.y + g1.x*w.x - g1.y*w.y;
    nu.y = g0.x*u.y + g0.y*u.x + g1.x*w.y + g1.y*w.x;
    nw.x = g2.x*u.x - g2.y*u.y + g3.x*w.x - g3.y*w.y;
    nw.y = g2.x*u.y + g2.y*u.x + g3.x*w.y + g3.y*w.x;
    u = nu; w = nw;
}

// ---------------------------------------------------------------------------
// Kernel 1: build T = U^T.  Round-17: TWO columns per block (grid 1024), all
// 4 blocks/CU resident from t=0 (grid == residency -> no block churn).
// Per column: one V buffer (no ping-pong).  Per layer:
//   Pass A: perm-read (ring perm closed form, validated r6-r16), gates on bits
//           10,9,8 in registers, barrier between read and scatter-write.
//   Pass B: own 8 consecutive elements; gates on bits 7..3 via ds_swizzle
//           (masks 16,8,4,2,1, validated r16); bits 2..0 in registers.
// Addressing, gate coefficient loads, and coefficient selects are shared
// across the two columns.  Layer 4's Pass B stores bf16 directly to global.
// ---------------------------------------------------------------------------
__global__ __launch_bounds__(256, 4) void build_ut(const float* __restrict__ w,
                                                   u16* __restrict__ ut_re,
                                                   u16* __restrict__ ut_im) {
    __shared__ alignas(16) float2 gg[55][4];               // 2x2 gates, row-major
    __shared__ alignas(16) float2 V[2][DIM + (DIM >> 4)];  // one per column
    const int tid  = threadIdx.x;
    const int lane = tid & 63;
    const int col0 = blockIdx.x * 2;

    if (tid < 55) {
        const int layer = tid / 11, q = tid - layer * 11;
        const float WM = 0.63245553203367586f;   // sqrt(2)*5^-0.5
        float hx = 0.5f * WM * w[33*layer + q];
        float hy = 0.5f * WM * w[33*layer + 11 + q];
        float hz = 0.5f * WM * w[33*layer + 22 + q];
        float cx = cosf(hx), sx = sinf(hx);
        float cy = cosf(hy), sy = sinf(hy);
        float cz = cosf(hz), sz = sinf(hz);
        c32 m00{cy*cx,  sy*sx}, m01{-sy*cx, -cy*sx};
        c32 m10{sy*cx, -cy*sx}, m11{ cy*cx, -sy*sx};
        c32 em{cz, -sz}, ep{cz, sz};
        c32 r0 = cmul(em, m00), r1 = cmul(em, m01);
        c32 r2 = cmul(ep, m10), r3 = cmul(ep, m11);
        gg[tid][0] = make_float2(r0.x, r0.y);
        gg[tid][1] = make_float2(r1.x, r1.y);
        gg[tid][2] = make_float2(r2.x, r2.y);
        gg[tid][3] = make_float2(r3.x, r3.y);
    }
    __syncthreads();

    // --- Layer 0: direct Kronecker product of a basis vector (per column) --
    #pragma unroll
    for (int c = 0; c < 2; ++c) {
        const int col = col0 + c;
        float2 p = gg[0][((((tid >> 7) & 1) << 1)) | ((col >> 10) & 1)];
        #pragma unroll
        for (int b = 9; b >= 3; --b) {
            float2 ge = gg[10 - b][(((tid >> (b - 3)) & 1) << 1) | ((col >> b) & 1)];
            p = cmulf2(p, ge);
        }
        const int c2 = (col >> 2) & 1, c1 = (col >> 1) & 1, c0 = col & 1;
        float2 a0  = cmulf2(p, gg[8][c2]);       // bit2 = 0
        float2 a1  = cmulf2(p, gg[8][2 | c2]);   // bit2 = 1
        float2 b00 = cmulf2(a0, gg[9][c1]);
        float2 b01 = cmulf2(a0, gg[9][2 | c1]);
        float2 b10 = cmulf2(a1, gg[9][c1]);
        float2 b11 = cmulf2(a1, gg[9][2 | c1]);
        float2 g0 = gg[10][c0], g1 = gg[10][2 | c0];
        const int sb = slot2(tid << 3);           // 8 consecutive slots
        V[c][sb + 0] = cmulf2(b00, g0);
        V[c][sb + 1] = cmulf2(b00, g1);
        V[c][sb + 2] = cmulf2(b01, g0);
        V[c][sb + 3] = cmulf2(b01, g1);
        V[c][sb + 4] = cmulf2(b10, g0);
        V[c][sb + 5] = cmulf2(b10, g1);
        V[c][sb + 6] = cmulf2(b11, g0);
        V[c][sb + 7] = cmulf2(b11, g1);
    }
    __syncthreads();

    for (int layer = 1; layer < 5; ++layer) {
        const int gb = layer * 11;

        // apply gates gq, gq+1, gq+2 to element-bits {2,1,0} of an 8-array
        auto tri = [&](float2 (&a)[8], int gq) {
            {   float2 g0 = gg[gq][0], g1 = gg[gq][1], g2 = gg[gq][2], g3 = gg[gq][3];
                bfly(g0,g1,g2,g3, a[0], a[4]); bfly(g0,g1,g2,g3, a[1], a[5]);
                bfly(g0,g1,g2,g3, a[2], a[6]); bfly(g0,g1,g2,g3, a[3], a[7]); }
            {   float2 g0 = gg[gq+1][0], g1 = gg[gq+1][1], g2 = gg[gq+1][2], g3 = gg[gq+1][3];
                bfly(g0,g1,g2,g3, a[0], a[2]); bfly(g0,g1,g2,g3, a[1], a[3]);
                bfly(g0,g1,g2,g3, a[4], a[6]); bfly(g0,g1,g2,g3, a[5], a[7]); }
            {   float2 g0 = gg[gq+2][0], g1 = gg[gq+2][1], g2 = gg[gq+2][2], g3 = gg[gq+2][3];
                bfly(g0,g1,g2,g3, a[0], a[1]); bfly(g0,g1,g2,g3, a[2], a[3]);
                bfly(g0,g1,g2,g3, a[4], a[5]); bfly(g0,g1,g2,g3, a[6], a[7]); }
        };

        // ---- Pass A: bits {10,9,8}; ring perm on read; shared addressing ----
        {
            float2 a0[8], a1[8]; int sl[8];
            #pragma unroll
            for (int j = 0; j < 8; ++j) {
                int e  = tid | (j << 8);                 // j0->bit8 j1->bit9 j2->bit10
                sl[j]  = slot2(e);
                int pe = (e ^ (e >> 1)) ^ ((e & 1) ? 0x600 : 0);
                int ps = slot2(pe);
                a0[j] = V[0][ps];
                a1[j] = V[1][ps];
            }
            __syncthreads();   // all perm reads done before scatter writes
            tri(a0, gb + 0);
            tri(a1, gb + 0);
            #pragma unroll
            for (int j = 0; j < 8; ++j) { V[0][sl[j]] = a0[j]; V[1][sl[j]] = a1[j]; }
            __syncthreads();
        }

        // ---- Pass B: home layout; bits 7..3 by ds_swizzle, 2..0 in reg ----
        {
            const int sb = slot2(tid << 3);
            float2 v0[8], v1[8];
            #pragma unroll
            for (int j = 0; j < 8; ++j) { v0[j] = V[0][sb + j]; v1[j] = V[1][sb + j]; }

            // gate on element-bit b via lane-xor mask M = 1<<(b-3); coeffs shared
            auto lane_gate = [&](int gq, int M, auto swz) {
                const bool hi = (lane & M) != 0;
                float2 g0 = gg[gq][0], g1 = gg[gq][1], g2 = gg[gq][2], g3 = gg[gq][3];
                float2 ca = hi ? g3 : g0;                // x own
                float2 cb = hi ? g2 : g1;                // x partner
                #pragma unroll
                for (int j = 0; j < 8; ++j) {
                    float2 p = swz(v0[j]);
                    float2 o = v0[j];
                    v0[j].x = ca.x*o.x - ca.y*o.y + cb.x*p.x - cb.y*p.y;
                    v0[j].y = ca.x*o.y + ca.y*o.x + cb.x*p.y + cb.y*p.x;
                    float2 q = swz(v1[j]);
                    float2 u = v1[j];
                    v1[j].x = ca.x*u.x - ca.y*u.y + cb.x*q.x - cb.y*q.y;
                    v1[j].y = ca.x*u.y + ca.y*u.x + cb.x*q.y + cb.y*q.x;
                }
            };
            lane_gate(gb + 3, 16, [](float2 t){ return swzx2<16>(t); });  // bit 7
            lane_gate(gb + 4,  8, [](float2 t){ return swzx2< 8>(t); });  // bit 6
            lane_gate(gb + 5,  4, [](float2 t){ return swzx2< 4>(t); });  // bit 5
            lane_gate(gb + 6,  2, [](float2 t){ return swzx2< 2>(t); });  // bit 4
            lane_gate(gb + 7,  1, [](float2 t){ return swzx2< 1>(t); });  // bit 3

            tri(v0, gb + 8);
            tri(v1, gb + 8);

            if (layer < 4) {
                #pragma unroll
                for (int j = 0; j < 8; ++j) { V[0][sb + j] = v0[j]; V[1][sb + j] = v1[j]; }
                __syncthreads();
            } else {
                const int base = tid << 3;
                u32x4 pr, pi;
                pr.x = (unsigned)f2bf(v0[0].x) | ((unsigned)f2bf(v0[1].x) << 16);
                pr.y = (unsigned)f2bf(v0[2].x) | ((unsigned)f2bf(v0[3].x) << 16);
                pr.z = (unsigned)f2bf(v0[4].x) | ((unsigned)f2bf(v0[5].x) << 16);
                pr.w = (unsigned)f2bf(v0[6].x) | ((unsigned)f2bf(v0[7].x) << 16);
                pi.x = (unsigned)f2bf(v0[0].y) | ((unsigned)f2bf(v0[1].y) << 16);
                pi.y = (unsigned)f2bf(v0[2].y) | ((unsigned)f2bf(v0[3].y) << 16);
                pi.z = (unsigned)f2bf(v0[4].y) | ((unsigned)f2bf(v0[5].y) << 16);
                pi.w = (unsigned)f2bf(v0[6].y) | ((unsigned)f2bf(v0[7].y) << 16);
                *(u32x4*)(ut_re + (size_t)col0 * DIM + base) = pr;
                *(u32x4*)(ut_im + (size_t)col0 * DIM + base) = pi;
                pr.x = (unsigned)f2bf(v1[0].x) | ((unsigned)f2bf(v1[1].x) << 16);
                pr.y = (unsigned)f2bf(v1[2].x) | ((unsigned)f2bf(v1[3].x) << 16);
                pr.z = (unsigned)f2bf(v1[4].x) | ((unsigned)f2bf(v1[5].x) << 16);
                pr.w = (unsigned)f2bf(v1[6].x) | ((unsigned)f2bf(v1[7].x) << 16);
                pi.x = (unsigned)f2bf(v1[0].y) | ((unsigned)f2bf(v1[1].y) << 16);
                pi.y = (unsigned)f2bf(v1[2].y) | ((unsigned)f2bf(v1[3].y) << 16);
                pi.z = (unsigned)f2bf(v1[4].y) | ((unsigned)f2bf(v1[5].y) << 16);
                pi.w = (unsigned)f2bf(v1[6].y) | ((unsigned)f2bf(v1[7].y) << 16);
                *(u32x4*)(ut_re + (size_t)(col0 + 1) * DIM + base) = pr;
                *(u32x4*)(ut_im + (size_t)(col0 + 1) * DIM + base) = pi;
            }
        }
    }
}

// ---------------------------------------------------------------------------
// Kernel 2: bf16 transpose (U^T -> U), 64x64 LDS tiles; z=0/1 selects re/im.
// z=2: converts X (fp32) -> bf16 xb plane (one 64x64 tile per block).
// ---------------------------------------------------------------------------
__global__ __launch_bounds__(256) void transpose2(const u16* __restrict__ sre,
                                                  const u16* __restrict__ sim,
                                                  u16* __restrict__ dre,
                                                  u16* __restrict__ dim_,
                                                  const float* __restrict__ x,
                                                  u16* __restrict__ xb) {
    const int bx = blockIdx.x * 64, by = blockIdx.y * 64;
    if (blockIdx.z == 2) {                       // x -> bf16 conversion tile
        for (int e = threadIdx.x; e < 512; e += 256) {
            int r = e >> 3, c8 = (e & 7) * 8;
            const float4* s4 = (const float4*)(x + (size_t)(by + r) * DIM + bx + c8);
            float4 v0 = s4[0], v1 = s4[1];
            u32x4 pk;
            pk.x = (unsigned)f2bf(v0.x) | ((unsigned)f2bf(v0.y) << 16);
            pk.y = (unsigned)f2bf(v0.z) | ((unsigned)f2bf(v0.w) << 16);
            pk.z = (unsigned)f2bf(v1.x) | ((unsigned)f2bf(v1.y) << 16);
            pk.w = (unsigned)f2bf(v1.z) | ((unsigned)f2bf(v1.w) << 16);
            *(u32x4*)(xb + (size_t)(by + r) * DIM + bx + c8) = pk;
        }
        return;
    }
    const u16* s = blockIdx.z ? sim : sre;
    u16*       d = blockIdx.z ? dim_ : dre;
    __shared__ alignas(16) u16 tile[64][66];
    for (int e = threadIdx.x; e < 1024; e += 256) {
        int r = e >> 4, c4 = (e & 15) * 4;
        uint2 v = *(const uint2*)(s + (size_t)(by + r) * DIM + bx + c4);
        u16* tp = &tile[r][c4];
        tp[0] = (u16)(v.x); tp[1] = (u16)(v.x >> 16);
        tp[2] = (u16)(v.y); tp[3] = (u16)(v.y >> 16);
    }
    __syncthreads();
    for (int e = threadIdx.x; e < 1024; e += 256) {
        int r = e >> 4, c4 = (e & 15) * 4;
        unsigned lo = (unsigned)tile[c4][r]     | ((unsigned)tile[c4+1][r] << 16);
        unsigned hi = (unsigned)tile[c4+2][r]   | ((unsigned)tile[c4+3][r] << 16);
        *(uint2*)(d + (size_t)(bx + r) * DIM + by + c4) = make_uint2(lo, hi);
    }
}

// ---------------------------------------------------------------------------
// GEMM stage 1 FUSED (single dispatch, stacked planes, 128x128, BK=64
// two-panel, double-buf): rows 0..2047 = Ure, 2048..4095 = Uim (contiguous
// workspace planes); dst rows likewise pt then qt.  [pt;qt] = [Ure;Uim] X^T.
// ---------------------------------------------------------------------------
__global__ __launch_bounds__(256, 2) void gemm_stage1(
        const u16* __restrict__ uStack,      // u_re base (u_im contiguous after)
        const u16* __restrict__ xb,
        u16* __restrict__ ptStack) {         // pt base (qt contiguous after)
    __shared__ alignas(16) u16 Ab[2][2][128*32], Bx[2][2][128*32]; // [buf][panel]
    const int tid  = threadIdx.x;
    const int lane = tid & 63, w = tid >> 6;
    const int m0 = blockIdx.y * 128, n0 = blockIdx.x * 128;   // m0 in [0,4096)
    const int wm = (w >> 1) * 64, wn = (w & 1) * 64;
    const int ml = lane & 15, quad = lane >> 4;

    f32x4 acc[4][4];
    #pragma unroll
    for (int i = 0; i < 4; ++i)
        #pragma unroll
        for (int j = 0; j < 4; ++j) {
            f32x4 z = {0.f, 0.f, 0.f, 0.f};
            acc[i][j] = z;
        }

    auto stage = [&](int b, int k0) {   // stages both 32-col panels (64 cols)
        #pragma unroll
        for (int pn = 0; pn < 2; ++pn) {
            #pragma unroll
            for (int t = 0; t < 2; ++t) {
                int ci = t * 256 + tid;          // 16B chunk = 8 bf16
                int r = ci >> 2, c = ci & 3;
                size_t goA = ((size_t)(m0 + r) * DIM + k0 + pn * 32) * 2 + c * 16;
                size_t goB = ((size_t)(n0 + r) * DIM + k0 + pn * 32) * 2 + c * 16;
                gl_lds16((const char*)uStack + goA, (char*)Ab[b][pn] + ci * 16);
                gl_lds16((const char*)xb     + goB, (char*)Bx[b][pn] + ci * 16);
            }
        }
    };

    stage(0, 0);
    __syncthreads();

    for (int k0 = 0; k0 < DIM; k0 += 64) {
        const int cb = (k0 >> 6) & 1;
        if (k0 + 64 < DIM) stage(cb ^ 1, k0 + 64);   // prefetch next 64-col tile

        #pragma unroll
        for (int pn = 0; pn < 2; ++pn) {
            bf16x8 af[4], bf[4];
            #pragma unroll
            for (int i = 0; i < 4; ++i) {
                af[i] = *(const bf16x8*)(Ab[cb][pn] + (wm + i*16 + ml) * 32 + quad * 8);
                bf[i] = *(const bf16x8*)(Bx[cb][pn] + (wn + i*16 + ml) * 32 + quad * 8);
            }
            #pragma unroll
            for (int i = 0; i < 4; ++i)
                #pragma unroll
                for (int j = 0; j < 4; ++j)
                    acc[i][j] = __builtin_amdgcn_mfma_f32_16x16x32_bf16(af[i], bf[j], acc[i][j], 0, 0, 0);
        }
        __syncthreads();
    }
    // C/D layout: col = lane&15, row = quad*4 + reg
    #pragma unroll
    for (int i = 0; i < 4; ++i)
        #pragma unroll
        for (int j = 0; j < 4; ++j) {
            int row = m0 + wm + i*16 + quad*4;
            int col = n0 + wn + j*16 + ml;
            #pragma unroll
            for (int r = 0; r < 4; ++r)
                ptStack[(size_t)(row + r) * DIM + col] = f2bf(acc[i][j][r]);
        }
}

// ---------------------------------------------------------------------------
// GEMM stage 2 FUSED (single dispatch, K=4096 over both planes), 128x64
// tiles -> grid 512 (2 blocks/CU) so the barrier drain overlaps across
// blocks.  out = Ure X Ure^T + Uim X Uim^T = Re(U X U^H), register
// accumulation, plain fp32 store -- no memset, no atomics.
// ---------------------------------------------------------------------------
__global__ __launch_bounds__(256, 2) void gemm_stage2_fused(
        const u16* __restrict__ ure, const u16* __restrict__ uim,
        const u16* __restrict__ pt, const u16* __restrict__ qt,
        float* __restrict__ out) {
    __shared__ alignas(16) u16 Ab[2][2][128*32], Bb[2][2][64*32];
    const int tid  = threadIdx.x;
    const int lane = tid & 63, w = tid >> 6;
    const int m0 = blockIdx.y * 128, n0 = blockIdx.x * 64;
    const int wm = (w >> 1) * 64, wn = (w & 1) * 32;
    const int ml = lane & 15, quad = lane >> 4;

    f32x4 acc[4][2];
    #pragma unroll
    for (int i = 0; i < 4; ++i)
        #pragma unroll
        for (int j = 0; j < 2; ++j) {
            f32x4 z = {0.f, 0.f, 0.f, 0.f};
            acc[i][j] = z;
        }

    auto stage = [&](int b, int kk) {            // kk in [0, 4096)
        const u16* A = (kk & DIM) ? uim : ure;
        const u16* B = (kk & DIM) ? qt  : pt;
        const int k0 = kk & (DIM - 1);
        #pragma unroll
        for (int pn = 0; pn < 2; ++pn) {
            #pragma unroll
            for (int t = 0; t < 2; ++t) {        // A: 128 rows = 512 chunks
                int ci = t * 256 + tid;
                int r = ci >> 2, c = ci & 3;
                size_t goA = ((size_t)(m0 + r) * DIM + k0 + pn * 32) * 2 + c * 16;
                gl_lds16((const char*)A + goA, (char*)Ab[b][pn] + ci * 16);
            }
            {                                    // B: 64 rows = 256 chunks
                int r = tid >> 2, c = tid & 3;
                size_t goB = ((size_t)(n0 + r) * DIM + k0 + pn * 32) * 2 + c * 16;
                gl_lds16((const char*)B + goB, (char*)Bb[b][pn] + tid * 16);
            }
        }
    };

    stage(0, 0);
    __syncthreads();

    for (int kk = 0; kk < 2 * DIM; kk += 64) {
        const int cb = (kk >> 6) & 1;
        if (kk + 64 < 2 * DIM) stage(cb ^ 1, kk + 64);

        #pragma unroll
        for (int pn = 0; pn < 2; ++pn) {
            bf16x8 af[4], bf[2];
            #pragma unroll
            for (int i = 0; i < 4; ++i)
                af[i] = *(const bf16x8*)(Ab[cb][pn] + (wm + i*16 + ml) * 32 + quad * 8);
            #pragma unroll
            for (int j = 0; j < 2; ++j)
                bf[j] = *(const bf16x8*)(Bb[cb][pn] + (wn + j*16 + ml) * 32 + quad * 8);
            #pragma unroll
            for (int i = 0; i < 4; ++i)
                #pragma unroll
                for (int j = 0; j < 2; ++j)
                    acc[i][j] = __builtin_amdgcn_mfma_f32_16x16x32_bf16(af[i], bf[j], acc[i][j], 0, 0, 0);
        }
        __syncthreads();
    }
    #pragma unroll
    for (int i = 0; i < 4; ++i)
        #pragma unroll
        for (int j = 0; j < 2; ++j) {
            int row = m0 + wm + i*16 + quad*4;
            int col = n0 + wn + j*16 + ml;
            #pragma unroll
            for (int r = 0; r < 4; ++r)
                out[(size_t)(row + r) * DIM + col] = acc[i][j][r];
        }
}

// ---------------------------------------------------------------------------
// Fallback (complex interleaved output) — insurance only, 128x128 1-buf LDS.
// ---------------------------------------------------------------------------
__global__ __launch_bounds__(256, 1) void gemm_stage2_cplx(
        const u16* __restrict__ ure, const u16* __restrict__ uim,
        const u16* __restrict__ pt, const u16* __restrict__ qt,
        float2* __restrict__ out, size_t out_lim) {
    __shared__ alignas(16) u16 Ar[128*32], Ai[128*32], Bp[128*32], Bq[128*32];
    const int tid  = threadIdx.x;
    const int lane = tid & 63, w = tid >> 6;
    const int m0 = blockIdx.y * 128, n0 = blockIdx.x * 128;
    const int wm = (w >> 1) * 64, wn = (w & 1) * 64;
    const int ml = lane & 15, quad = lane >> 4;

    f32x4 accR[4][4], accI[4][4];
    #pragma unroll
    for (int i = 0; i < 4; ++i)
        #pragma unroll
        for (int j = 0; j < 4; ++j) {
            f32x4 z = {0.f, 0.f, 0.f, 0.f};
            accR[i][j] = z; accI[i][j] = z;
        }

    for (int k0 = 0; k0 < DIM; k0 += 32) {
        #pragma unroll
        for (int t = 0; t < 2; ++t) {
            int ci = t * 256 + tid;
            int r = ci >> 2, c = ci & 3;
            size_t goA = ((size_t)(m0 + r) * DIM + k0) * 2 + c * 16;
            size_t goB = ((size_t)(n0 + r) * DIM + k0) * 2 + c * 16;
            gl_lds16((const char*)ure + goA, (char*)Ar + ci * 16);
            gl_lds16((const char*)uim + goA, (char*)Ai + ci * 16);
            gl_lds16((const char*)pt  + goB, (char*)Bp + ci * 16);
            gl_lds16((const char*)qt  + goB, (char*)Bq + ci * 16);
        }
        __syncthreads();
        bf16x8 ar[4], ai[4], bp[4], bq[4];
        #pragma unroll
        for (int i = 0; i < 4; ++i) {
            ar[i] = *(const bf16x8*)(Ar + (wm + i*16 + ml) * 32 + quad * 8);
            ai[i] = *(const bf16x8*)(Ai + (wm + i*16 + ml) * 32 + quad * 8);
            bp[i] = *(const bf16x8*)(Bp + (wn + i*16 + ml) * 32 + quad * 8);
            bq[i] = *(const bf16x8*)(Bq + (wn + i*16 + ml) * 32 + quad * 8);
        }
        #pragma unroll
        for (int i = 0; i < 4; ++i)
            #pragma unroll
            for (int j = 0; j < 4; ++j) {
                accR[i][j] = __builtin_amdgcn_mfma_f32_16x16x32_bf16(ar[i], bp[j], accR[i][j], 0, 0, 0);
                accR[i][j] = __builtin_amdgcn_mfma_f32_16x16x32_bf16(ai[i], bq[j], accR[i][j], 0, 0, 0);
                accI[i][j] = __builtin_amdgcn_mfma_f32_16x16x32_bf16(ai[i], bp[j], accI[i][j], 0, 0, 0);
                f32x4 t2 = __builtin_amdgcn_mfma_f32_16x16x32_bf16(ar[i], bq[j], {0.f,0.f,0.f,0.f}, 0, 0, 0);
                accI[i][j] -= t2;
            }
        __syncthreads();
    }
    #pragma unroll
    for (int i = 0; i < 4; ++i)
        #pragma unroll
        for (int j = 0; j < 4; ++j) {
            int row = m0 + wm + i*16 + quad*4;
            int col = n0 + wn + j*16 + ml;
            #pragma unroll
            for (int r = 0; r < 4; ++r) {
                size_t idx = (size_t)(row + r) * DIM + col;
                if (idx < out_lim)
                    out[idx] = make_float2(accR[i][j][r], accI[i][j][r]);
            }
        }
}

// ---------------------------------------------------------------------------
extern "C" void kernel_launch(void* const* d_in, const int* in_sizes, int n_in,
                              void* d_out, int out_size, void* d_ws, size_t ws_size,
                              hipStream_t stream) {
    int xi = (in_sizes[0] >= in_sizes[1]) ? 0 : 1;
    const float* x = (const float*)d_in[xi];
    const float* w = (const float*)d_in[1 - xi];

    char* ws = (char*)d_ws;
    const size_t P = (size_t)DIM * DIM * 2;   // one bf16 plane = 8 MiB
    if (ws_size < 4 * P) return;

    u16* ut_re = (u16*)(ws);
    u16* ut_im = (u16*)(ws + P);
    u16* u_re  = (u16*)(ws + 2*P);
    u16* u_im  = (u16*)(ws + 3*P);
    u16* pt    = ut_re;   // reuse after transpose
    u16* qt    = ut_im;
    // bf16 X plane: ws plane 5 if it fits, else d_out's first 8 MiB
    // (d_out is dead until after gemm_stage1 in both output paths).
    u16* xb = (ws_size >= 5 * P) ? (u16*)(ws + 4*P) : (u16*)d_out;

    build_ut<<<DIM/2, 256, 0, stream>>>(w, ut_re, ut_im);
    transpose2<<<dim3(32, 32, 3), 256, 0, stream>>>(ut_re, ut_im, u_re, u_im, x, xb);
    // fused: [pt;qt] = [Ure;Uim] X^T  (stacked 4096-row GEMM, one dispatch)
    gemm_stage1<<<dim3(16, 32), 256, 0, stream>>>(u_re, xb, pt);

    if (out_size == DIM * DIM) {
        gemm_stage2_fused<<<dim3(32, 16), 256, 0, stream>>>(u_re, u_im, pt, qt,
                                                            (float*)d_out);
    } else {
        gemm_stage2_cplx<<<dim3(16, 16), 256, 0, stream>>>(u_re, u_im, pt, qt,
                                                           (float2*)d_out,
                                                           (size_t)out_size / 2);
    }
}